// Round 1
// baseline (1816.336 us; speedup 1.0000x reference)
//
#include <hip/hip_runtime.h>

#define VOCAB 32000
#define NTOK  1024
#define HS    2048
#define HT    4096

typedef __attribute__((ext_vector_type(8))) short bf16x8;
typedef __attribute__((ext_vector_type(4))) float f32x4;

__device__ __forceinline__ unsigned short f2bf(float f){
  unsigned u = __float_as_uint(f);
  u += 0x7fffu + ((u >> 16) & 1u);   // round-to-nearest-even
  return (unsigned short)(u >> 16);
}
__device__ __forceinline__ unsigned pack2(float a, float b){
  return (unsigned)f2bf(a) | ((unsigned)f2bf(b) << 16);
}
__device__ __forceinline__ float blo(unsigned u){ return __uint_as_float(u << 16); }
__device__ __forceinline__ float bhi(unsigned u){ return __uint_as_float(u & 0xffff0000u); }

// ---------------- fp32 -> bf16 (activations) ----------------
__global__ __launch_bounds__(256) void cvt_f32_bf16(const float* __restrict__ in,
                                                    unsigned short* __restrict__ out, int n4){
  int i = blockIdx.x * 256 + threadIdx.x;
  if (i < n4){
    float4 v = ((const float4*)in)[i];
    uint2 o;
    o.x = pack2(v.x, v.y);
    o.y = pack2(v.z, v.w);
    ((uint2*)out)[i] = o;
  }
}

// ---------------- GEMM: C[m,v] = sum_k A[m,k]*W[v,k] + bias[v] ----------------
// A: [NTOK,K] bf16 (pre-converted). W: [VOCAB,K] fp32, converted to bf16 in-flight.
// Tile 128x128x32, 256 threads = 4 waves, each wave a 64x64 sub-tile (4x4 MFMA 16x16x32).
__global__ __launch_bounds__(256, 2) void gemm_logits(
    const unsigned short* __restrict__ A,
    const float* __restrict__ W,
    const float* __restrict__ bias,
    unsigned short* __restrict__ C,   // [NTOK, VOCAB] bf16
    int K)
{
  constexpr int LDT = 40;  // padded LDS row stride (elements): 80B, 16B-aligned, 2-way banks (free)
  __shared__ unsigned short As[128 * LDT];
  __shared__ unsigned short Bs[128 * LDT];

  const int tid  = threadIdx.x;
  const int lane = tid & 63;
  const int wave = tid >> 6;
  const int m0 = blockIdx.y * 128;
  const int v0 = blockIdx.x * 128;
  const int wm = (wave >> 1) * 64;
  const int wn = (wave & 1) * 64;

  // staging assignments
  const int a_row = tid >> 2, a_kb = tid & 3;   // A: 16B chunks, rows 0..63 (+64 for 2nd)
  const int w_row = tid >> 1, w_half = tid & 1; // W: 16 floats (64B) per thread

  const f32x4 zero = {0.f, 0.f, 0.f, 0.f};
  f32x4 acc[4][4];
#pragma unroll
  for (int i = 0; i < 4; i++)
#pragma unroll
    for (int j = 0; j < 4; j++) acc[i][j] = zero;

  const int NT = K >> 5;

  uint4 a0, a1;
  float4 w0, w1, w2, w3;
  {
    const unsigned short* ap = A + (size_t)(m0 + a_row) * K + a_kb * 8;
    a0 = *(const uint4*)(ap);
    a1 = *(const uint4*)(ap + (size_t)64 * K);
    const float* wp = W + (size_t)(v0 + w_row) * K + w_half * 16;
    w0 = *(const float4*)(wp);
    w1 = *(const float4*)(wp + 4);
    w2 = *(const float4*)(wp + 8);
    w3 = *(const float4*)(wp + 12);
  }

  const int ar = lane & 15, kq = lane >> 4;

  for (int kt = 0; kt < NT; ++kt){
    __syncthreads();
    // regs -> LDS
    *(uint4*)(As + a_row * LDT + a_kb * 8)        = a0;
    *(uint4*)(As + (64 + a_row) * LDT + a_kb * 8) = a1;
    {
      unsigned q0 = pack2(w0.x, w0.y), q1 = pack2(w0.z, w0.w);
      unsigned q2 = pack2(w1.x, w1.y), q3 = pack2(w1.z, w1.w);
      unsigned q4 = pack2(w2.x, w2.y), q5 = pack2(w2.z, w2.w);
      unsigned q6 = pack2(w3.x, w3.y), q7 = pack2(w3.z, w3.w);
      *(uint4*)(Bs + w_row * LDT + w_half * 16)     = make_uint4(q0, q1, q2, q3);
      *(uint4*)(Bs + w_row * LDT + w_half * 16 + 8) = make_uint4(q4, q5, q6, q7);
    }
    __syncthreads();
    // prefetch next tile into regs (overlaps with MFMA below)
    if (kt + 1 < NT){
      const int k0 = (kt + 1) << 5;
      const unsigned short* ap = A + (size_t)(m0 + a_row) * K + k0 + a_kb * 8;
      a0 = *(const uint4*)(ap);
      a1 = *(const uint4*)(ap + (size_t)64 * K);
      const float* wp = W + (size_t)(v0 + w_row) * K + k0 + w_half * 16;
      w0 = *(const float4*)(wp);
      w1 = *(const float4*)(wp + 4);
      w2 = *(const float4*)(wp + 8);
      w3 = *(const float4*)(wp + 12);
    }
    // LDS -> frags -> MFMA
    bf16x8 af[4], bf[4];
#pragma unroll
    for (int i = 0; i < 4; i++){
      af[i] = *(const bf16x8*)(As + (wm + i * 16 + ar) * LDT + kq * 8);
      bf[i] = *(const bf16x8*)(Bs + (wn + i * 16 + ar) * LDT + kq * 8);
    }
#pragma unroll
    for (int i = 0; i < 4; i++)
#pragma unroll
      for (int j = 0; j < 4; j++)
        acc[i][j] = __builtin_amdgcn_mfma_f32_16x16x32_bf16(af[i], bf[j], acc[i][j], 0, 0, 0);
  }

  // epilogue: C/D layout col = lane&15, row = (lane>>4)*4 + reg  [m89-verified]
  const int rq = lane >> 4;
#pragma unroll
  for (int j = 0; j < 4; j++){
    const int v = v0 + wn + j * 16 + ar;
    const float bv = bias[v];
#pragma unroll
    for (int i = 0; i < 4; i++){
      const int mbase = m0 + wm + i * 16 + rq * 4;
#pragma unroll
      for (int r = 0; r < 4; r++){
        C[(size_t)(mbase + r) * VOCAB + v] = f2bf(acc[i][j][r] + bv);
      }
    }
  }
}

// ---------------- per-row logsumexp over VOCAB ----------------
__global__ __launch_bounds__(256) void row_stats(const unsigned short* __restrict__ L,
                                                 float* __restrict__ lse){
  const int row = blockIdx.x;
  const uint4* p = (const uint4*)(L + (size_t)row * VOCAB);
  float mx = -3.0e38f;
  for (int i = threadIdx.x; i < VOCAB / 8; i += 256){
    uint4 u = p[i];
    float f0 = blo(u.x), f1 = bhi(u.x), f2 = blo(u.y), f3 = bhi(u.y);
    float f4 = blo(u.z), f5 = bhi(u.z), f6 = blo(u.w), f7 = bhi(u.w);
    mx = fmaxf(mx, fmaxf(fmaxf(fmaxf(f0, f1), fmaxf(f2, f3)),
                         fmaxf(fmaxf(f4, f5), fmaxf(f6, f7))));
  }
#pragma unroll
  for (int off = 1; off < 64; off <<= 1) mx = fmaxf(mx, __shfl_xor(mx, off));
  __shared__ float sm[4], ss[4];
  if ((threadIdx.x & 63) == 0) sm[threadIdx.x >> 6] = mx;
  __syncthreads();
  mx = fmaxf(fmaxf(sm[0], sm[1]), fmaxf(sm[2], sm[3]));
  float s = 0.f;
  for (int i = threadIdx.x; i < VOCAB / 8; i += 256){
    uint4 u = p[i];
    s += __expf(blo(u.x) - mx) + __expf(bhi(u.x) - mx)
       + __expf(blo(u.y) - mx) + __expf(bhi(u.y) - mx)
       + __expf(blo(u.z) - mx) + __expf(bhi(u.z) - mx)
       + __expf(blo(u.w) - mx) + __expf(bhi(u.w) - mx);
  }
#pragma unroll
  for (int off = 1; off < 64; off <<= 1) s += __shfl_xor(s, off);
  if ((threadIdx.x & 63) == 0) ss[threadIdx.x >> 6] = s;
  __syncthreads();
  if (threadIdx.x == 0) lse[row] = mx + __logf(ss[0] + ss[1] + ss[2] + ss[3]);
}

// ---------------- JSD + CE, accumulate scalar ----------------
__device__ __forceinline__ float jsd_term(float sl, float tl, float ls, float lt){
  float slp = sl - ls, tlp = tl - lt;
  float sp = __expf(slp), tp = __expf(tlp);
  float lm = __logf(0.5f * (sp + tp));
  return 0.5f * (tp * (tlp - lm) + sp * (slp - lm));  // BETA = 0.5
}

__global__ __launch_bounds__(256) void jsd_ce(
    const unsigned short* __restrict__ Ls, const unsigned short* __restrict__ Lt,
    const float* __restrict__ lse_s, const float* __restrict__ lse_t,
    const int* __restrict__ labels, float* __restrict__ out)
{
  const int row = blockIdx.x;
  const float ls = lse_s[row], lt = lse_t[row];
  const uint4* ps = (const uint4*)(Ls + (size_t)row * VOCAB);
  const uint4* pt = (const uint4*)(Lt + (size_t)row * VOCAB);
  float acc = 0.f;
  for (int i = threadIdx.x; i < VOCAB / 8; i += 256){
    uint4 us = ps[i], ut = pt[i];
    acc += jsd_term(blo(us.x), blo(ut.x), ls, lt) + jsd_term(bhi(us.x), bhi(ut.x), ls, lt);
    acc += jsd_term(blo(us.y), blo(ut.y), ls, lt) + jsd_term(bhi(us.y), bhi(ut.y), ls, lt);
    acc += jsd_term(blo(us.z), blo(ut.z), ls, lt) + jsd_term(bhi(us.z), bhi(ut.z), ls, lt);
    acc += jsd_term(blo(us.w), blo(ut.w), ls, lt) + jsd_term(bhi(us.w), bhi(ut.w), ls, lt);
  }
#pragma unroll
  for (int off = 1; off < 64; off <<= 1) acc += __shfl_xor(acc, off);
  __shared__ float sa[4];
  if ((threadIdx.x & 63) == 0) sa[threadIdx.x >> 6] = acc;
  __syncthreads();
  if (threadIdx.x == 0){
    float tot = sa[0] + sa[1] + sa[2] + sa[3];
    float res = tot * (0.5f / (float)NTOK);          // WEIGHT_SOFT * jsd / N
    int lab = labels[row];
    if (lab != -100){
      float sl_lab = __uint_as_float((unsigned)Ls[(size_t)row * VOCAB + lab] << 16);
      res += (ls - sl_lab) * (0.5f / (float)NTOK);   // WEIGHT_HARD * nll / N
    }
    atomicAdd(out, res);
  }
}

extern "C" void kernel_launch(void* const* d_in, const int* in_sizes, int n_in,
                              void* d_out, int out_size, void* d_ws, size_t ws_size,
                              hipStream_t stream){
  (void)in_sizes; (void)n_in; (void)out_size; (void)ws_size;
  const float* s_in = (const float*)d_in[0];
  const float* s_w  = (const float*)d_in[1];
  const float* t_in = (const float*)d_in[2];
  const float* t_w  = (const float*)d_in[3];
  const int*   lab  = (const int*)d_in[4];
  const float* s_b  = (const float*)d_in[5];
  const float* t_b  = (const float*)d_in[6];
  float* out = (float*)d_out;

  char* ws = (char*)d_ws;
  size_t off = 0;
  auto alloc = [&](size_t b){ void* p = ws + off; off += (b + 255) & ~(size_t)255; return p; };
  unsigned short* As_bf = (unsigned short*)alloc((size_t)NTOK * HS * 2);
  unsigned short* At_bf = (unsigned short*)alloc((size_t)NTOK * HT * 2);
  unsigned short* Ls    = (unsigned short*)alloc((size_t)NTOK * VOCAB * 2);
  unsigned short* Lt    = (unsigned short*)alloc((size_t)NTOK * VOCAB * 2);
  float* lse_s = (float*)alloc(NTOK * 4);
  float* lse_t = (float*)alloc(NTOK * 4);

  hipMemsetAsync(d_out, 0, sizeof(float), stream);  // d_out is poisoned before each launch
  cvt_f32_bf16<<<NTOK * HS / 4 / 256, 256, 0, stream>>>(s_in, As_bf, NTOK * HS / 4);
  cvt_f32_bf16<<<NTOK * HT / 4 / 256, 256, 0, stream>>>(t_in, At_bf, NTOK * HT / 4);
  dim3 g(VOCAB / 128, NTOK / 128);
  gemm_logits<<<g, 256, 0, stream>>>(As_bf, s_w, s_b, Ls, HS);
  gemm_logits<<<g, 256, 0, stream>>>(At_bf, t_w, t_b, Lt, HT);
  row_stats<<<NTOK, 256, 0, stream>>>(Ls, lse_s);
  row_stats<<<NTOK, 256, 0, stream>>>(Lt, lse_t);
  jsd_ce<<<NTOK, 256, 0, stream>>>(Ls, Lt, lse_s, lse_t, lab, out);
}